// Round 2
// baseline (959.872 us; speedup 1.0000x reference)
//
#include <hip/hip_runtime.h>
#include <math.h>

// Problem constants (from reference)
#define NB   512    // batch
#define NQ   64     // queries
#define NCC  1000   // candidates
#define EE   128    // embed
#define HH   8      // heads
#define HDD  16     // head dim
#define NL   3      // GAT layers
#define DD   4      // cluster depth
#define KP   136    // LDS pitch (ushort) for compat K hi/lo staging (272B rows, 16B-aligned)
#define CCH  64     // candidates per compat block
#define XP   136    // LDS pitch (ushort) for gat [64][128] bufs
#define VP   72     // LDS pitch (ushort) for gat V^T [128][64]

typedef __bf16 bf16x8 __attribute__((ext_vector_type(8)));
typedef unsigned short u16x8 __attribute__((ext_vector_type(8)));
typedef unsigned short u16x4 __attribute__((ext_vector_type(4)));
typedef unsigned int   u32x4 __attribute__((ext_vector_type(4)));
typedef float f32x4  __attribute__((ext_vector_type(4)));
typedef float f32x16 __attribute__((ext_vector_type(16)));

__device__ __forceinline__ unsigned short f2bf(float x) {
  union { float f; unsigned u; } v; v.f = x;
  unsigned r = (v.u + 0x7fffu + ((v.u >> 16) & 1u)) >> 16;
  return (unsigned short)r;
}
__device__ __forceinline__ float bf2f(unsigned short h) {
  union { unsigned u; float f; } v; v.u = ((unsigned)h) << 16;
  return v.f;
}
__device__ __forceinline__ bf16x8 ld8(const unsigned short* p) {
  return __builtin_bit_cast(bf16x8, *(const u16x8*)p);
}
// 10*tanh(s*0.25) = 10 - 20/(exp(s*0.5)+1); exact saturation at +/-10.
__device__ __forceinline__ float tanh10_q(float s) {
  const float e = __expf(s * 0.5f);
  return 10.f - 20.f * __builtin_amdgcn_rcpf(e + 1.f);
}

// ---------------------------------------------------------------------------
// Kernel 0: weight prep. Transpose + bf16 hi/lo split for all 14 matrices:
//   m = l*4 + {0:Wq,1:Wk,2:Wv,3:Wo} for l in 0..2, m=12: final Wq, m=13: final Wk.
// Output layout per mat: [n*128 + k] so MFMA B-fragments read 8 contiguous k's.
// m=13 region doubles as the compat kernel's wkt_hi/wkt_lo.
// ---------------------------------------------------------------------------
__global__ __launch_bounds__(256) void wprep_kernel(
    const float* __restrict__ gWq, const float* __restrict__ gWk,
    const float* __restrict__ gWv, const float* __restrict__ gWo,
    const float* __restrict__ Wq,  const float* __restrict__ Wk,
    unsigned short* __restrict__ gwt_hi, unsigned short* __restrict__ gwt_lo)
{
  const int idx = blockIdx.x * 256 + threadIdx.x;   // 896 blocks -> 14*16384
  const int m = idx >> 14;
  const int r = idx & 16383;
  const int k = r >> 7, n = r & 127;
  const float* src;
  if (m < 12) {
    const int l = m >> 2, w = m & 3;
    src = (w == 0 ? gWq : w == 1 ? gWk : w == 2 ? gWv : gWo) + l * 16384;
  } else if (m == 12) src = Wq;
  else                src = Wk;
  const float v = src[k * EE + n];
  const unsigned short h = f2bf(v);
  gwt_hi[(size_t)m * 16384 + n * EE + k] = h;
  gwt_lo[(size_t)m * 16384 + n * EE + k] = f2bf(v - bf2f(h));
}

// ---------------------------------------------------------------------------
// Kernel 1: MFMA GAT (3 fused MHA layers) + final query projection.
// One block per batch, 512 threads = 8 waves.  (unchanged this round)
// ---------------------------------------------------------------------------
__global__ __launch_bounds__(512, 1) void gat_query_mfma(
    const float* __restrict__ hin,
    const unsigned short* __restrict__ gwt_hi,
    const unsigned short* __restrict__ gwt_lo,
    const float* __restrict__ gbq, const float* __restrict__ gbk,
    const float* __restrict__ gbv, const float* __restrict__ gbo,
    const float* __restrict__ bq,
    float* __restrict__ query)
{
  __shared__ unsigned short XH[64 * XP], XL[64 * XP];
  __shared__ unsigned short QH[64 * XP], QL[64 * XP];
  __shared__ unsigned short KH[64 * XP], KL[64 * XP];   // doubles as O hi/lo
  __shared__ unsigned short VTH[128 * VP], VTL[128 * VP];

  const int b    = blockIdx.x;
  const int tid  = threadIdx.x;
  const int wid  = tid >> 6;
  const int lane = tid & 63;
  const int l15  = lane & 15;
  const int quad = lane >> 4;
  const int col  = lane & 31;
  const int hi32 = lane >> 5;

  // load + split X
  for (int idx = tid; idx < NQ * EE; idx += 512) {
    const float v = hin[(size_t)b * NQ * EE + idx];
    const int r = idx >> 7, c = idx & 127;
    const unsigned short h = f2bf(v);
    XH[r * XP + c] = h;
    XL[r * XP + c] = f2bf(v - bf2f(h));
  }
  __syncthreads();

  const int mt = wid >> 1, nh = wid & 1;
  const int r0 = mt * 16;

  for (int l = 0; l < NL; ++l) {
    // ---------------- P1: Q,K,V projections ----------------
    {
      bf16x8 axh[4], axl[4];
      #pragma unroll
      for (int k4 = 0; k4 < 4; ++k4) {
        axh[k4] = ld8(&XH[(r0 + l15) * XP + k4 * 32 + quad * 8]);
        axl[k4] = ld8(&XL[(r0 + l15) * XP + k4 * 32 + quad * 8]);
      }
      #pragma unroll
      for (int m = 0; m < 3; ++m) {
        const unsigned short* WH = gwt_hi + (size_t)(l * 4 + m) * 16384;
        const unsigned short* WL = gwt_lo + (size_t)(l * 4 + m) * 16384;
        const float* bias = (m == 0 ? gbq : (m == 1 ? gbk : gbv)) + l * EE;
        #pragma unroll
        for (int ntl = 0; ntl < 4; ++ntl) {
          const int n = (nh * 4 + ntl) * 16 + l15;
          f32x4 acc = (f32x4){0.f, 0.f, 0.f, 0.f};
          #pragma unroll
          for (int k4 = 0; k4 < 4; ++k4) {
            const int k0 = k4 * 32 + quad * 8;
            const bf16x8 bh = ld8(&WH[n * EE + k0]);
            const bf16x8 bl = ld8(&WL[n * EE + k0]);
            acc = __builtin_amdgcn_mfma_f32_16x16x32_bf16(axh[k4], bh, acc, 0, 0, 0);
            acc = __builtin_amdgcn_mfma_f32_16x16x32_bf16(axh[k4], bl, acc, 0, 0, 0);
            acc = __builtin_amdgcn_mfma_f32_16x16x32_bf16(axl[k4], bh, acc, 0, 0, 0);
          }
          const float bv = bias[n];
          if (m == 2) {
            u16x4 hv, lv;
            #pragma unroll
            for (int r = 0; r < 4; ++r) {
              const float v = acc[r] + bv;
              const unsigned short h = f2bf(v);
              hv[r] = h;
              lv[r] = f2bf(v - bf2f(h));
            }
            *(u16x4*)&VTH[n * VP + r0 + quad * 4] = hv;
            *(u16x4*)&VTL[n * VP + r0 + quad * 4] = lv;
          } else {
            unsigned short* DH = m ? KH : QH;
            unsigned short* DL = m ? KL : QL;
            #pragma unroll
            for (int r = 0; r < 4; ++r) {
              const int crow = r0 + quad * 4 + r;
              const float v = acc[r] + bv;
              const unsigned short h = f2bf(v);
              DH[crow * XP + n] = h;
              DL[crow * XP + n] = f2bf(v - bf2f(h));
            }
          }
        }
      }
    }
    __syncthreads();

    // ---------------- P2: attention, head = wid ----------------
    {
      const int hwid = wid;
      const int hb = hwid * 16 + hi32 * 8;
      bf16x8 akh[2], akl[2], qbh[2], qbl[2];
      #pragma unroll
      for (int t = 0; t < 2; ++t) {
        akh[t] = ld8(&KH[(t * 32 + col) * XP + hb]);
        akl[t] = ld8(&KL[(t * 32 + col) * XP + hb]);
        qbh[t] = ld8(&QH[(t * 32 + col) * XP + hb]);
        qbl[t] = ld8(&QL[(t * 32 + col) * XP + hb]);
      }

      bf16x8 pah[2][4], pal[2][4];   // PV A-frags [qt][ks]
      #pragma unroll
      for (int qt = 0; qt < 2; ++qt) {
        f32x16 sAcc[2];
        #pragma unroll
        for (int kt = 0; kt < 2; ++kt) {
          #pragma unroll
          for (int i = 0; i < 16; ++i) sAcc[kt][i] = 0.f;
          sAcc[kt] = __builtin_amdgcn_mfma_f32_32x32x16_bf16(akh[kt], qbh[qt], sAcc[kt], 0, 0, 0);
          sAcc[kt] = __builtin_amdgcn_mfma_f32_32x32x16_bf16(akh[kt], qbl[qt], sAcc[kt], 0, 0, 0);
          sAcc[kt] = __builtin_amdgcn_mfma_f32_32x32x16_bf16(akl[kt], qbh[qt], sAcc[kt], 0, 0, 0);
        }
        float p[2][16];
        float mx = -INFINITY;
        #pragma unroll
        for (int kt = 0; kt < 2; ++kt)
          #pragma unroll
          for (int r = 0; r < 16; ++r) {
            p[kt][r] = sAcc[kt][r] * 0.25f;
            mx = fmaxf(mx, p[kt][r]);
          }
        mx = fmaxf(mx, __shfl_xor(mx, 32));
        float sum = 0.f;
        #pragma unroll
        for (int kt = 0; kt < 2; ++kt)
          #pragma unroll
          for (int r = 0; r < 16; ++r) {
            p[kt][r] = exp2f((p[kt][r] - mx) * 1.4426950408889634f);
            sum += p[kt][r];
          }
        sum += __shfl_xor(sum, 32);
        const float inv = 1.f / sum;

        unsigned pkh[2][8], pkl[2][8], swh[2][8], swl[2][8];
        #pragma unroll
        for (int kt = 0; kt < 2; ++kt)
          #pragma unroll
          for (int w = 0; w < 8; ++w) {
            const float v0 = p[kt][w * 2]     * inv;
            const float v1 = p[kt][w * 2 + 1] * inv;
            const unsigned short h0 = f2bf(v0);
            const unsigned short l0 = f2bf(v0 - bf2f(h0));
            const unsigned short h1 = f2bf(v1);
            const unsigned short l1 = f2bf(v1 - bf2f(h1));
            pkh[kt][w] = (unsigned)h0 | ((unsigned)h1 << 16);
            pkl[kt][w] = (unsigned)l0 | ((unsigned)l1 << 16);
            swh[kt][w] = (unsigned)__shfl_xor((int)pkh[kt][w], 32);
            swl[kt][w] = (unsigned)__shfl_xor((int)pkl[kt][w], 32);
          }
        const bool top = (hi32 != 0);
        #pragma unroll
        for (int ks = 0; ks < 4; ++ks) {
          const int kt = ks >> 1, hf = ks & 1;
          u32x4 wh, wl;
          wh[0] = top ? swh[kt][4 * hf + 2] : pkh[kt][4 * hf + 0];
          wh[1] = top ? swh[kt][4 * hf + 3] : pkh[kt][4 * hf + 1];
          wh[2] = top ? pkh[kt][4 * hf + 2] : swh[kt][4 * hf + 0];
          wh[3] = top ? pkh[kt][4 * hf + 3] : swh[kt][4 * hf + 1];
          wl[0] = top ? swl[kt][4 * hf + 2] : pkl[kt][4 * hf + 0];
          wl[1] = top ? swl[kt][4 * hf + 3] : pkl[kt][4 * hf + 1];
          wl[2] = top ? pkl[kt][4 * hf + 2] : swl[kt][4 * hf + 0];
          wl[3] = top ? pkl[kt][4 * hf + 3] : swl[kt][4 * hf + 1];
          pah[qt][ks] = __builtin_bit_cast(bf16x8, wh);
          pal[qt][ks] = __builtin_bit_cast(bf16x8, wl);
        }
      }

      bf16x8 bvh[4], bvl[4];
      const int vrow = hwid * 16 + (col & 15);
      #pragma unroll
      for (int ks = 0; ks < 4; ++ks) {
        bvh[ks] = ld8(&VTH[vrow * VP + ks * 16 + hi32 * 8]);
        bvl[ks] = ld8(&VTL[vrow * VP + ks * 16 + hi32 * 8]);
      }
      f32x16 accO[2];
      #pragma unroll
      for (int qt = 0; qt < 2; ++qt) {
        #pragma unroll
        for (int i = 0; i < 16; ++i) accO[qt][i] = 0.f;
        #pragma unroll
        for (int ks = 0; ks < 4; ++ks) {
          accO[qt] = __builtin_amdgcn_mfma_f32_32x32x16_bf16(pah[qt][ks], bvh[ks], accO[qt], 0, 0, 0);
          accO[qt] = __builtin_amdgcn_mfma_f32_32x32x16_bf16(pah[qt][ks], bvl[ks], accO[qt], 0, 0, 0);
          accO[qt] = __builtin_amdgcn_mfma_f32_32x32x16_bf16(pal[qt][ks], bvh[ks], accO[qt], 0, 0, 0);
        }
      }
      if (col < 16) {
        #pragma unroll
        for (int qt = 0; qt < 2; ++qt)
          #pragma unroll
          for (int r = 0; r < 16; ++r) {
            const int qrow = qt * 32 + (r & 3) + 8 * (r >> 2) + 4 * hi32;
            const float v = accO[qt][r];
            const unsigned short h = f2bf(v);
            KH[qrow * XP + hwid * 16 + col] = h;
            KL[qrow * XP + hwid * 16 + col] = f2bf(v - bf2f(h));
          }
      }
    }
    __syncthreads();

    // ---------------- P3: X += O@Wo + bo ----------------
    {
      bf16x8 aoh[4], aol[4];
      #pragma unroll
      for (int k4 = 0; k4 < 4; ++k4) {
        aoh[k4] = ld8(&KH[(r0 + l15) * XP + k4 * 32 + quad * 8]);
        aol[k4] = ld8(&KL[(r0 + l15) * XP + k4 * 32 + quad * 8]);
      }
      const unsigned short* WH = gwt_hi + (size_t)(l * 4 + 3) * 16384;
      const unsigned short* WL = gwt_lo + (size_t)(l * 4 + 3) * 16384;
      #pragma unroll
      for (int ntl = 0; ntl < 4; ++ntl) {
        const int n = (nh * 4 + ntl) * 16 + l15;
        f32x4 acc = (f32x4){0.f, 0.f, 0.f, 0.f};
        #pragma unroll
        for (int k4 = 0; k4 < 4; ++k4) {
          const int k0 = k4 * 32 + quad * 8;
          const bf16x8 bh = ld8(&WH[n * EE + k0]);
          const bf16x8 bl = ld8(&WL[n * EE + k0]);
          acc = __builtin_amdgcn_mfma_f32_16x16x32_bf16(aoh[k4], bh, acc, 0, 0, 0);
          acc = __builtin_amdgcn_mfma_f32_16x16x32_bf16(aoh[k4], bl, acc, 0, 0, 0);
          acc = __builtin_amdgcn_mfma_f32_16x16x32_bf16(aol[k4], bh, acc, 0, 0, 0);
        }
        const float bv = gbo[l * EE + n];
        #pragma unroll
        for (int r = 0; r < 4; ++r) {
          const int crow = r0 + quad * 4 + r;
          const float xo = bf2f(XH[crow * XP + n]) + bf2f(XL[crow * XP + n]);
          const float v = xo + acc[r] + bv;
          const unsigned short h = f2bf(v);
          XH[crow * XP + n] = h;
          XL[crow * XP + n] = f2bf(v - bf2f(h));
        }
      }
    }
    __syncthreads();
  }

  // ---------------- final query projection ----------------
  {
    bf16x8 axh[4], axl[4];
    #pragma unroll
    for (int k4 = 0; k4 < 4; ++k4) {
      axh[k4] = ld8(&XH[(r0 + l15) * XP + k4 * 32 + quad * 8]);
      axl[k4] = ld8(&XL[(r0 + l15) * XP + k4 * 32 + quad * 8]);
    }
    const unsigned short* WH = gwt_hi + (size_t)12 * 16384;
    const unsigned short* WL = gwt_lo + (size_t)12 * 16384;
    #pragma unroll
    for (int ntl = 0; ntl < 4; ++ntl) {
      const int n = (nh * 4 + ntl) * 16 + l15;
      f32x4 acc = (f32x4){0.f, 0.f, 0.f, 0.f};
      #pragma unroll
      for (int k4 = 0; k4 < 4; ++k4) {
        const int k0 = k4 * 32 + quad * 8;
        const bf16x8 bh = ld8(&WH[n * EE + k0]);
        const bf16x8 bl = ld8(&WL[n * EE + k0]);
        acc = __builtin_amdgcn_mfma_f32_16x16x32_bf16(axh[k4], bh, acc, 0, 0, 0);
        acc = __builtin_amdgcn_mfma_f32_16x16x32_bf16(axh[k4], bl, acc, 0, 0, 0);
        acc = __builtin_amdgcn_mfma_f32_16x16x32_bf16(axl[k4], bh, acc, 0, 0, 0);
      }
      const float bv = bq[n];
      #pragma unroll
      for (int r = 0; r < 4; ++r) {
        const int crow = r0 + quad * 4 + r;
        query[((size_t)b * NQ + crow) * EE + n] = acc[r] + bv;
      }
    }
  }
}

// ---------------------------------------------------------------------------
// Kernel 2: MFMA compat. One block per (64-candidate chunk, batch).
// Chunk halved 128->64 so LDS = 35 KB -> 4 blocks/CU (16 waves) for latency
// hiding; fast tanh epilogue; cin loads issued before convert/MFMA.
// ---------------------------------------------------------------------------
__global__ __launch_bounds__(256, 4) void compat_mfma_kernel(
    const float* __restrict__ cin,
    const float* __restrict__ query,
    const unsigned char* __restrict__ mask,
    const unsigned short* __restrict__ wkt_hi,
    const unsigned short* __restrict__ wkt_lo,
    const float* __restrict__ bk,
    float* __restrict__ compat_out,
    float* __restrict__ compts)
{
  __shared__ unsigned short Khi[CCH * KP];
  __shared__ unsigned short Klo[CCH * KP];
  __shared__ float colsum[CCH];

  const int ch   = blockIdx.x;          // 0..15 candidate chunk (64 cands)
  const int b    = blockIdx.y;          // batch
  const int tid  = threadIdx.x;
  const int wave = tid >> 6;
  const int lane = tid & 63;
  const int l15  = lane & 15;
  const int quad = lane >> 4;

  if (tid < CCH) colsum[tid] = 0.f;

  // ---------------- Phase A: key projection (64 rows, wave owns 16) -------
  {
    // issue all global loads of this wave's A-tile first (latency hiding)
    float xv[4][8];
    {
      int grow = ch * CCH + wave * 16 + l15;
      if (grow > NCC - 1) grow = NCC - 1;          // tail clamp (cols masked later)
      const float* srow = &cin[((size_t)b * NCC + grow) * EE + quad * 8];
      #pragma unroll
      for (int k4 = 0; k4 < 4; ++k4) {
        *(float4*)&xv[k4][0] = *(const float4*)&srow[k4 * 32 + 0];
        *(float4*)&xv[k4][4] = *(const float4*)&srow[k4 * 32 + 4];
      }
    }
    bf16x8 ahi[4], alo[4];
    #pragma unroll
    for (int k4 = 0; k4 < 4; ++k4) {
      u16x8 h, lo;
      #pragma unroll
      for (int j = 0; j < 8; ++j) {
        unsigned short hb = f2bf(xv[k4][j]);
        h[j] = hb;
        lo[j] = f2bf(xv[k4][j] - bf2f(hb));
      }
      ahi[k4] = __builtin_bit_cast(bf16x8, h);
      alo[k4] = __builtin_bit_cast(bf16x8, lo);
    }

    #pragma unroll
    for (int nt = 0; nt < 8; ++nt) {
      const int n = nt * 16 + l15;
      f32x4 acc = (f32x4){0.f, 0.f, 0.f, 0.f};
      #pragma unroll
      for (int k4 = 0; k4 < 4; ++k4) {
        const int k0 = k4 * 32 + quad * 8;
        const bf16x8 bhi = __builtin_bit_cast(bf16x8, *(const u16x8*)&wkt_hi[n * EE + k0]);
        const bf16x8 blo = __builtin_bit_cast(bf16x8, *(const u16x8*)&wkt_lo[n * EE + k0]);
        acc = __builtin_amdgcn_mfma_f32_16x16x32_bf16(ahi[k4], bhi, acc, 0, 0, 0);
        acc = __builtin_amdgcn_mfma_f32_16x16x32_bf16(ahi[k4], blo, acc, 0, 0, 0);
        acc = __builtin_amdgcn_mfma_f32_16x16x32_bf16(alo[k4], bhi, acc, 0, 0, 0);
      }
      const float bkv = bk[n];
      #pragma unroll
      for (int r = 0; r < 4; ++r) {
        const int crow = wave * 16 + quad * 4 + r;
        const float v = acc[r] + bkv;
        const unsigned short hb = f2bf(v);
        Khi[crow * KP + n] = hb;
        Klo[crow * KP + n] = f2bf(v - bf2f(hb));
      }
    }
  }
  __syncthreads();

  // ---------------- Phase B: S = Q @ K^T ----------------
  {
    bf16x8 qhi[4], qlo[4];
    #pragma unroll
    for (int k4 = 0; k4 < 4; ++k4) {
      const float* src = &query[((size_t)b * NQ + wave * 16 + l15) * EE + k4 * 32 + quad * 8];
      const float4 x0 = *(const float4*)&src[0];
      const float4 x1 = *(const float4*)&src[4];
      float xq[8] = {x0.x, x0.y, x0.z, x0.w, x1.x, x1.y, x1.z, x1.w};
      u16x8 h, lo;
      #pragma unroll
      for (int j = 0; j < 8; ++j) {
        unsigned short hb = f2bf(xq[j]);
        h[j] = hb;
        lo[j] = f2bf(xq[j] - bf2f(hb));
      }
      qhi[k4] = __builtin_bit_cast(bf16x8, h);
      qlo[k4] = __builtin_bit_cast(bf16x8, lo);
    }

    f32x4 acc[4];
    #pragma unroll
    for (int nt = 0; nt < 4; ++nt) acc[nt] = (f32x4){0.f, 0.f, 0.f, 0.f};

    #pragma unroll
    for (int k4 = 0; k4 < 4; ++k4) {
      const int k0 = k4 * 32 + quad * 8;
      #pragma unroll
      for (int nt = 0; nt < 4; ++nt) {
        const int crow = nt * 16 + l15;
        const bf16x8 khf = __builtin_bit_cast(bf16x8, *(const u16x8*)&Khi[crow * KP + k0]);
        const bf16x8 klf = __builtin_bit_cast(bf16x8, *(const u16x8*)&Klo[crow * KP + k0]);
        acc[nt] = __builtin_amdgcn_mfma_f32_16x16x32_bf16(qhi[k4], khf, acc[nt], 0, 0, 0);
        acc[nt] = __builtin_amdgcn_mfma_f32_16x16x32_bf16(qhi[k4], klf, acc[nt], 0, 0, 0);
        acc[nt] = __builtin_amdgcn_mfma_f32_16x16x32_bf16(qlo[k4], khf, acc[nt], 0, 0, 0);
      }
    }

    // epilogue: fast tanh*10, mask, store, column sums
    #pragma unroll
    for (int nt = 0; nt < 4; ++nt) {
      const int jloc  = nt * 16 + l15;
      const int jglob = ch * CCH + jloc;
      const bool jok  = (jglob < NCC);
      float s4 = 0.f;
      #pragma unroll
      for (int r = 0; r < 4; ++r) {
        const int q = wave * 16 + quad * 4 + r;
        float v = tanh10_q(acc[nt][r]);
        if (jok) {
          if (mask[((size_t)b * NQ + q) * (NCC + 1) + 1 + jglob]) v = -INFINITY;
          compat_out[((size_t)b * NQ + q) * NCC + jglob] = v;
        }
        s4 += v;
      }
      s4 += __shfl_xor(s4, 16);
      s4 += __shfl_xor(s4, 32);
      if (lane < 16 && jok) atomicAdd(&colsum[jloc], s4);
    }
  }
  __syncthreads();

  if (tid < CCH) {
    const int jglob = ch * CCH + tid;
    if (jglob < NCC)
      compts[(size_t)b * 1024 + jglob] = colsum[tid] * (1.0f / (float)NQ);
  }
}

// ---------------------------------------------------------------------------
// Kernel 3: per-batch argmax over compts with cluster masking. (unchanged)
// ---------------------------------------------------------------------------
__global__ __launch_bounds__(256) void argmax_kernel(
    const float* __restrict__ compts,
    const unsigned char* __restrict__ clusters,
    const int* __restrict__ depot_id,
    float* __restrict__ out)
{
  __shared__ float redv[256];
  __shared__ int   redi[256];
  const int b   = blockIdx.x;
  const int tid = threadIdx.x;
  const int dep = depot_id[0];
  float bestv = -INFINITY;
  int   besti = 0x7fffffff;
  for (int j = tid; j < NCC; j += 256) {
    float t = compts[(size_t)b * 1024 + j];
    if (clusters[((size_t)b * DD + dep) * NCC + j]) t = -INFINITY;
    if (t > bestv || (t == bestv && j < besti)) { bestv = t; besti = j; }
  }
  redv[tid] = bestv; redi[tid] = besti;
  __syncthreads();
  if (tid == 0) {
    float bv = redv[0]; int bi = redi[0];
    for (int t = 1; t < 256; ++t) {
      if (redv[t] > bv || (redv[t] == bv && redi[t] < bi)) {
        bv = redv[t]; bi = redi[t];
      }
    }
    out[b] = (float)bi;
  }
}

// ---------------------------------------------------------------------------
extern "C" void kernel_launch(void* const* d_in, const int* in_sizes, int n_in,
                              void* d_out, int out_size, void* d_ws, size_t ws_size,
                              hipStream_t stream) {
  const float* hin      = (const float*)d_in[0];
  const float* cin      = (const float*)d_in[1];
  const unsigned char* mask     = (const unsigned char*)d_in[2];
  const unsigned char* clusters = (const unsigned char*)d_in[3];
  const int*   depot    = (const int*)d_in[4];
  const float* gWq = (const float*)d_in[5];
  const float* gbq = (const float*)d_in[6];
  const float* gWk = (const float*)d_in[7];
  const float* gbk = (const float*)d_in[8];
  const float* gWv = (const float*)d_in[9];
  const float* gbv = (const float*)d_in[10];
  const float* gWo = (const float*)d_in[11];
  const float* gbo = (const float*)d_in[12];
  const float* Wq  = (const float*)d_in[13];
  const float* bq  = (const float*)d_in[14];
  const float* Wk  = (const float*)d_in[15];
  const float* bk  = (const float*)d_in[16];
  float* out   = (float*)d_out;
  float* compat_out = out + NB;

  // ws layout: query f32 (16 MiB) | compts (2 MiB) | gwt_hi (448 KiB) | gwt_lo (448 KiB)
  float*          query  = (float*)d_ws;
  float*          compts = (float*)((char*)d_ws + (size_t)NB * NQ * EE * 4);
  unsigned short* gwt_hi = (unsigned short*)((char*)compts + (size_t)NB * 1024 * 4);
  unsigned short* gwt_lo = gwt_hi + (size_t)14 * 16384;
  unsigned short* wkt_hi = gwt_hi + (size_t)13 * 16384;   // mat 13 = final Wk
  unsigned short* wkt_lo = gwt_lo + (size_t)13 * 16384;

  wprep_kernel<<<896, 256, 0, stream>>>(gWq, gWk, gWv, gWo, Wq, Wk, gwt_hi, gwt_lo);
  gat_query_mfma<<<NB, 512, 0, stream>>>(hin, gwt_hi, gwt_lo,
                                         gbq, gbk, gbv, gbo, bq, query);
  compat_mfma_kernel<<<dim3(16, NB), 256, 0, stream>>>(
      cin, query, mask, wkt_hi, wkt_lo, bk, compat_out, compts);
  argmax_kernel<<<NB, 256, 0, stream>>>(compts, clusters, depot, out);
}

// Round 3
// 828.490 us; speedup vs baseline: 1.1586x; 1.1586x over previous
//
#include <hip/hip_runtime.h>
#include <math.h>

// Problem constants (from reference)
#define NB   512    // batch
#define NQ   64     // queries
#define NCC  1000   // candidates
#define EE   128    // embed
#define HH   8      // heads
#define HDD  16     // head dim
#define NL   3      // GAT layers
#define DD   4      // cluster depth
#define CCH  64     // candidates per compat block
#define XP   136    // LDS pitch (ushort) for gat [64][128] bufs
#define VP   72     // LDS pitch (ushort) for gat V^T [128][64]

typedef __bf16 bf16x8 __attribute__((ext_vector_type(8)));
typedef unsigned short u16x8 __attribute__((ext_vector_type(8)));
typedef unsigned short u16x4 __attribute__((ext_vector_type(4)));
typedef unsigned int   u32x4 __attribute__((ext_vector_type(4)));
typedef float f32x4  __attribute__((ext_vector_type(4)));
typedef float f32x16 __attribute__((ext_vector_type(16)));

__device__ __forceinline__ unsigned short f2bf(float x) {
  union { float f; unsigned u; } v; v.f = x;
  unsigned r = (v.u + 0x7fffu + ((v.u >> 16) & 1u)) >> 16;
  return (unsigned short)r;
}
__device__ __forceinline__ float bf2f(unsigned short h) {
  union { unsigned u; float f; } v; v.u = ((unsigned)h) << 16;
  return v.f;
}
__device__ __forceinline__ bf16x8 ld8(const unsigned short* p) {
  return __builtin_bit_cast(bf16x8, *(const u16x8*)p);
}
// 10*tanh(s*0.25) = 10 - 20/(exp(s*0.5)+1); exact saturation at +/-10.
__device__ __forceinline__ float tanh10_q(float s) {
  const float e = __expf(s * 0.5f);
  return 10.f - 20.f * __builtin_amdgcn_rcpf(e + 1.f);
}
// XOR-swizzled byte offset inside a [64][128]-u16 (256B-row) LDS tile (T2/m214)
__device__ __forceinline__ int swz(int row, int cb) {
  return row * 256 + (cb ^ ((row & 7) << 4));
}

// ---------------------------------------------------------------------------
// Kernel 0: weight prep.
//  m = l*4 + {0:Wq,1:Wk,2:Wv,3:Wo} for l in 0..2, m=12: final Wq  -> gwt (transposed
//  [n][k] bf16 hi/lo).  m=13: final Wk -> FRAGMENT-LINEAR wkf layout:
//  wkf[((nt*4+k4)*64 + lane)*8 + j] = Wk^T[nt*16+(lane&15)][k4*32+(lane>>4)*8+j]
//  so compat B-fragment loads are lane-consecutive 16B (fully coalesced).
// ---------------------------------------------------------------------------
__global__ __launch_bounds__(256) void wprep_kernel(
    const float* __restrict__ gWq, const float* __restrict__ gWk,
    const float* __restrict__ gWv, const float* __restrict__ gWo,
    const float* __restrict__ Wq,  const float* __restrict__ Wk,
    unsigned short* __restrict__ gwt_hi, unsigned short* __restrict__ gwt_lo,
    unsigned short* __restrict__ wkf_hi, unsigned short* __restrict__ wkf_lo)
{
  const int idx = blockIdx.x * 256 + threadIdx.x;   // 896 blocks -> 14*16384
  const int m = idx >> 14;
  const int r = idx & 16383;
  const int k = r >> 7, n = r & 127;
  const float* src;
  if (m < 12) {
    const int l = m >> 2, w = m & 3;
    src = (w == 0 ? gWq : w == 1 ? gWk : w == 2 ? gWv : gWo) + l * 16384;
  } else if (m == 12) src = Wq;
  else                src = Wk;
  const float v = src[k * EE + n];
  const unsigned short h  = f2bf(v);
  const unsigned short lo = f2bf(v - bf2f(h));
  if (m < 13) {
    gwt_hi[(size_t)m * 16384 + n * EE + k] = h;
    gwt_lo[(size_t)m * 16384 + n * EE + k] = lo;
  } else {
    const int nt = n >> 4, l15 = n & 15;
    const int k4 = k >> 5, qd = (k >> 3) & 3, j = k & 7;
    const int off = (((nt * 4 + k4) * 64) + qd * 16 + l15) * 8 + j;
    wkf_hi[off] = h;
    wkf_lo[off] = lo;
  }
}

// ---------------------------------------------------------------------------
// Kernel 1: MFMA GAT (3 fused MHA layers) + final query projection.
// One block per batch, 512 threads = 8 waves.
// NEW: epilogue stores the final query SPLIT into fragment-linear qhi/qlo
// (so compat's Q loads are coalesced b128, no per-chunk split).
// ---------------------------------------------------------------------------
__global__ __launch_bounds__(512, 1) void gat_query_mfma(
    const float* __restrict__ hin,
    const unsigned short* __restrict__ gwt_hi,
    const unsigned short* __restrict__ gwt_lo,
    const float* __restrict__ gbq, const float* __restrict__ gbk,
    const float* __restrict__ gbv, const float* __restrict__ gbo,
    const float* __restrict__ bq,
    unsigned short* __restrict__ qhi, unsigned short* __restrict__ qlo)
{
  __shared__ unsigned short XH[64 * XP], XL[64 * XP];
  __shared__ unsigned short QH[64 * XP], QL[64 * XP];
  __shared__ unsigned short KH[64 * XP], KL[64 * XP];   // doubles as O hi/lo
  __shared__ unsigned short VTH[128 * VP], VTL[128 * VP];

  const int b    = blockIdx.x;
  const int tid  = threadIdx.x;
  const int wid  = tid >> 6;
  const int lane = tid & 63;
  const int l15  = lane & 15;
  const int quad = lane >> 4;
  const int col  = lane & 31;
  const int hi32 = lane >> 5;

  // load + split X
  for (int idx = tid; idx < NQ * EE; idx += 512) {
    const float v = hin[(size_t)b * NQ * EE + idx];
    const int r = idx >> 7, c = idx & 127;
    const unsigned short h = f2bf(v);
    XH[r * XP + c] = h;
    XL[r * XP + c] = f2bf(v - bf2f(h));
  }
  __syncthreads();

  const int mt = wid >> 1, nh = wid & 1;
  const int r0 = mt * 16;

  for (int l = 0; l < NL; ++l) {
    // ---------------- P1: Q,K,V projections ----------------
    {
      bf16x8 axh[4], axl[4];
      #pragma unroll
      for (int k4 = 0; k4 < 4; ++k4) {
        axh[k4] = ld8(&XH[(r0 + l15) * XP + k4 * 32 + quad * 8]);
        axl[k4] = ld8(&XL[(r0 + l15) * XP + k4 * 32 + quad * 8]);
      }
      #pragma unroll
      for (int m = 0; m < 3; ++m) {
        const unsigned short* WH = gwt_hi + (size_t)(l * 4 + m) * 16384;
        const unsigned short* WL = gwt_lo + (size_t)(l * 4 + m) * 16384;
        const float* bias = (m == 0 ? gbq : (m == 1 ? gbk : gbv)) + l * EE;
        #pragma unroll
        for (int ntl = 0; ntl < 4; ++ntl) {
          const int n = (nh * 4 + ntl) * 16 + l15;
          f32x4 acc = (f32x4){0.f, 0.f, 0.f, 0.f};
          #pragma unroll
          for (int k4 = 0; k4 < 4; ++k4) {
            const int k0 = k4 * 32 + quad * 8;
            const bf16x8 bh = ld8(&WH[n * EE + k0]);
            const bf16x8 bl = ld8(&WL[n * EE + k0]);
            acc = __builtin_amdgcn_mfma_f32_16x16x32_bf16(axh[k4], bh, acc, 0, 0, 0);
            acc = __builtin_amdgcn_mfma_f32_16x16x32_bf16(axh[k4], bl, acc, 0, 0, 0);
            acc = __builtin_amdgcn_mfma_f32_16x16x32_bf16(axl[k4], bh, acc, 0, 0, 0);
          }
          const float bv = bias[n];
          if (m == 2) {
            u16x4 hv, lv;
            #pragma unroll
            for (int r = 0; r < 4; ++r) {
              const float v = acc[r] + bv;
              const unsigned short h = f2bf(v);
              hv[r] = h;
              lv[r] = f2bf(v - bf2f(h));
            }
            *(u16x4*)&VTH[n * VP + r0 + quad * 4] = hv;
            *(u16x4*)&VTL[n * VP + r0 + quad * 4] = lv;
          } else {
            unsigned short* DH = m ? KH : QH;
            unsigned short* DL = m ? KL : QL;
            #pragma unroll
            for (int r = 0; r < 4; ++r) {
              const int crow = r0 + quad * 4 + r;
              const float v = acc[r] + bv;
              const unsigned short h = f2bf(v);
              DH[crow * XP + n] = h;
              DL[crow * XP + n] = f2bf(v - bf2f(h));
            }
          }
        }
      }
    }
    __syncthreads();

    // ---------------- P2: attention, head = wid ----------------
    {
      const int hwid = wid;
      const int hb = hwid * 16 + hi32 * 8;
      bf16x8 akh[2], akl[2], qbh[2], qbl[2];
      #pragma unroll
      for (int t = 0; t < 2; ++t) {
        akh[t] = ld8(&KH[(t * 32 + col) * XP + hb]);
        akl[t] = ld8(&KL[(t * 32 + col) * XP + hb]);
        qbh[t] = ld8(&QH[(t * 32 + col) * XP + hb]);
        qbl[t] = ld8(&QL[(t * 32 + col) * XP + hb]);
      }

      bf16x8 pah[2][4], pal[2][4];   // PV A-frags [qt][ks]
      #pragma unroll
      for (int qt = 0; qt < 2; ++qt) {
        f32x16 sAcc[2];
        #pragma unroll
        for (int kt = 0; kt < 2; ++kt) {
          #pragma unroll
          for (int i = 0; i < 16; ++i) sAcc[kt][i] = 0.f;
          sAcc[kt] = __builtin_amdgcn_mfma_f32_32x32x16_bf16(akh[kt], qbh[qt], sAcc[kt], 0, 0, 0);
          sAcc[kt] = __builtin_amdgcn_mfma_f32_32x32x16_bf16(akh[kt], qbl[qt], sAcc[kt], 0, 0, 0);
          sAcc[kt] = __builtin_amdgcn_mfma_f32_32x32x16_bf16(akl[kt], qbh[qt], sAcc[kt], 0, 0, 0);
        }
        float p[2][16];
        float mx = -INFINITY;
        #pragma unroll
        for (int kt = 0; kt < 2; ++kt)
          #pragma unroll
          for (int r = 0; r < 16; ++r) {
            p[kt][r] = sAcc[kt][r] * 0.25f;
            mx = fmaxf(mx, p[kt][r]);
          }
        mx = fmaxf(mx, __shfl_xor(mx, 32));
        float sum = 0.f;
        #pragma unroll
        for (int kt = 0; kt < 2; ++kt)
          #pragma unroll
          for (int r = 0; r < 16; ++r) {
            p[kt][r] = exp2f((p[kt][r] - mx) * 1.4426950408889634f);
            sum += p[kt][r];
          }
        sum += __shfl_xor(sum, 32);
        const float inv = 1.f / sum;

        unsigned pkh[2][8], pkl[2][8], swh[2][8], swl[2][8];
        #pragma unroll
        for (int kt = 0; kt < 2; ++kt)
          #pragma unroll
          for (int w = 0; w < 8; ++w) {
            const float v0 = p[kt][w * 2]     * inv;
            const float v1 = p[kt][w * 2 + 1] * inv;
            const unsigned short h0 = f2bf(v0);
            const unsigned short l0 = f2bf(v0 - bf2f(h0));
            const unsigned short h1 = f2bf(v1);
            const unsigned short l1 = f2bf(v1 - bf2f(h1));
            pkh[kt][w] = (unsigned)h0 | ((unsigned)h1 << 16);
            pkl[kt][w] = (unsigned)l0 | ((unsigned)l1 << 16);
            swh[kt][w] = (unsigned)__shfl_xor((int)pkh[kt][w], 32);
            swl[kt][w] = (unsigned)__shfl_xor((int)pkl[kt][w], 32);
          }
        const bool top = (hi32 != 0);
        #pragma unroll
        for (int ks = 0; ks < 4; ++ks) {
          const int kt = ks >> 1, hf = ks & 1;
          u32x4 wh, wl;
          wh[0] = top ? swh[kt][4 * hf + 2] : pkh[kt][4 * hf + 0];
          wh[1] = top ? swh[kt][4 * hf + 3] : pkh[kt][4 * hf + 1];
          wh[2] = top ? pkh[kt][4 * hf + 2] : swh[kt][4 * hf + 0];
          wh[3] = top ? pkh[kt][4 * hf + 3] : swh[kt][4 * hf + 1];
          wl[0] = top ? swl[kt][4 * hf + 2] : pkl[kt][4 * hf + 0];
          wl[1] = top ? swl[kt][4 * hf + 3] : pkl[kt][4 * hf + 1];
          wl[2] = top ? pkl[kt][4 * hf + 2] : swl[kt][4 * hf + 0];
          wl[3] = top ? pkl[kt][4 * hf + 3] : swl[kt][4 * hf + 1];
          pah[qt][ks] = __builtin_bit_cast(bf16x8, wh);
          pal[qt][ks] = __builtin_bit_cast(bf16x8, wl);
        }
      }

      bf16x8 bvh[4], bvl[4];
      const int vrow = hwid * 16 + (col & 15);
      #pragma unroll
      for (int ks = 0; ks < 4; ++ks) {
        bvh[ks] = ld8(&VTH[vrow * VP + ks * 16 + hi32 * 8]);
        bvl[ks] = ld8(&VTL[vrow * VP + ks * 16 + hi32 * 8]);
      }
      f32x16 accO[2];
      #pragma unroll
      for (int qt = 0; qt < 2; ++qt) {
        #pragma unroll
        for (int i = 0; i < 16; ++i) accO[qt][i] = 0.f;
        #pragma unroll
        for (int ks = 0; ks < 4; ++ks) {
          accO[qt] = __builtin_amdgcn_mfma_f32_32x32x16_bf16(pah[qt][ks], bvh[ks], accO[qt], 0, 0, 0);
          accO[qt] = __builtin_amdgcn_mfma_f32_32x32x16_bf16(pah[qt][ks], bvl[ks], accO[qt], 0, 0, 0);
          accO[qt] = __builtin_amdgcn_mfma_f32_32x32x16_bf16(pal[qt][ks], bvh[ks], accO[qt], 0, 0, 0);
        }
      }
      if (col < 16) {
        #pragma unroll
        for (int qt = 0; qt < 2; ++qt)
          #pragma unroll
          for (int r = 0; r < 16; ++r) {
            const int qrow = qt * 32 + (r & 3) + 8 * (r >> 2) + 4 * hi32;
            const float v = accO[qt][r];
            const unsigned short h = f2bf(v);
            KH[qrow * XP + hwid * 16 + col] = h;
            KL[qrow * XP + hwid * 16 + col] = f2bf(v - bf2f(h));
          }
      }
    }
    __syncthreads();

    // ---------------- P3: X += O@Wo + bo ----------------
    {
      bf16x8 aoh[4], aol[4];
      #pragma unroll
      for (int k4 = 0; k4 < 4; ++k4) {
        aoh[k4] = ld8(&KH[(r0 + l15) * XP + k4 * 32 + quad * 8]);
        aol[k4] = ld8(&KL[(r0 + l15) * XP + k4 * 32 + quad * 8]);
      }
      const unsigned short* WH = gwt_hi + (size_t)(l * 4 + 3) * 16384;
      const unsigned short* WL = gwt_lo + (size_t)(l * 4 + 3) * 16384;
      #pragma unroll
      for (int ntl = 0; ntl < 4; ++ntl) {
        const int n = (nh * 4 + ntl) * 16 + l15;
        f32x4 acc = (f32x4){0.f, 0.f, 0.f, 0.f};
        #pragma unroll
        for (int k4 = 0; k4 < 4; ++k4) {
          const int k0 = k4 * 32 + quad * 8;
          const bf16x8 bh = ld8(&WH[n * EE + k0]);
          const bf16x8 bl = ld8(&WL[n * EE + k0]);
          acc = __builtin_amdgcn_mfma_f32_16x16x32_bf16(aoh[k4], bh, acc, 0, 0, 0);
          acc = __builtin_amdgcn_mfma_f32_16x16x32_bf16(aoh[k4], bl, acc, 0, 0, 0);
          acc = __builtin_amdgcn_mfma_f32_16x16x32_bf16(aol[k4], bh, acc, 0, 0, 0);
        }
        const float bv = gbo[l * EE + n];
        #pragma unroll
        for (int r = 0; r < 4; ++r) {
          const int crow = r0 + quad * 4 + r;
          const float xo = bf2f(XH[crow * XP + n]) + bf2f(XL[crow * XP + n]);
          const float v = xo + acc[r] + bv;
          const unsigned short h = f2bf(v);
          XH[crow * XP + n] = h;
          XL[crow * XP + n] = f2bf(v - bf2f(h));
        }
      }
    }
    __syncthreads();
  }

  // ---------------- final query projection -> QH/QL (split) ----------------
  {
    bf16x8 axh[4], axl[4];
    #pragma unroll
    for (int k4 = 0; k4 < 4; ++k4) {
      axh[k4] = ld8(&XH[(r0 + l15) * XP + k4 * 32 + quad * 8]);
      axl[k4] = ld8(&XL[(r0 + l15) * XP + k4 * 32 + quad * 8]);
    }
    const unsigned short* WH = gwt_hi + (size_t)12 * 16384;
    const unsigned short* WL = gwt_lo + (size_t)12 * 16384;
    #pragma unroll
    for (int ntl = 0; ntl < 4; ++ntl) {
      const int n = (nh * 4 + ntl) * 16 + l15;
      f32x4 acc = (f32x4){0.f, 0.f, 0.f, 0.f};
      #pragma unroll
      for (int k4 = 0; k4 < 4; ++k4) {
        const int k0 = k4 * 32 + quad * 8;
        const bf16x8 bh = ld8(&WH[n * EE + k0]);
        const bf16x8 bl = ld8(&WL[n * EE + k0]);
        acc = __builtin_amdgcn_mfma_f32_16x16x32_bf16(axh[k4], bh, acc, 0, 0, 0);
        acc = __builtin_amdgcn_mfma_f32_16x16x32_bf16(axh[k4], bl, acc, 0, 0, 0);
        acc = __builtin_amdgcn_mfma_f32_16x16x32_bf16(axl[k4], bh, acc, 0, 0, 0);
      }
      const float bv = bq[n];
      #pragma unroll
      for (int r = 0; r < 4; ++r) {
        const int crow = r0 + quad * 4 + r;
        const float v = acc[r] + bv;
        const unsigned short h = f2bf(v);
        QH[crow * XP + n] = h;
        QL[crow * XP + n] = f2bf(v - bf2f(h));
      }
    }
  }
  __syncthreads();

  // repack query to fragment-linear qhi/qlo: [b][wc][k4][lane][8]
  for (int it = 0; it < 4; ++it) {
    const int idx  = it * 512 + tid;       // 0..2047
    const int part = idx >> 10;            // 0 = hi, 1 = lo
    const int id2  = idx & 1023;
    const int wc   = id2 >> 8;
    const int k4   = (id2 >> 6) & 3;
    const int ln   = id2 & 63;
    const int row  = wc * 16 + (ln & 15);
    const int colu = k4 * 32 + (ln >> 4) * 8;
    const unsigned short* S = part ? QL : QH;
    const u16x8 v = *(const u16x8*)&S[row * XP + colu];
    unsigned short* D = part ? qlo : qhi;
    *(u16x8*)&D[((((size_t)b * 4 + wc) * 4 + k4) * 64 + ln) * 8] = v;
  }
}

// ---------------------------------------------------------------------------
// Kernel 2: MFMA compat. One block per (64-candidate chunk, batch).
//  - cin staged COALESCED -> split once -> XOR-swizzled [64][128] bf16 hi/lo
//    LDS tiles (TH/TL).
//  - Phase A: K = C@Wk + bk; Wk frags are fragment-linear (coalesced b128);
//    K overwrites TH/TL IN PLACE (each wave touches only its own 16 rows).
//  - Phase B: S = Q@K^T with pre-split coalesced Q frags; fast-tanh epilogue.
// LDS: 2*16KB + 256B = 32.3 KB -> 4 blocks/CU (16 waves).
// ---------------------------------------------------------------------------
__global__ __launch_bounds__(256, 4) void compat_mfma_kernel(
    const float* __restrict__ cin,
    const unsigned short* __restrict__ qhi,
    const unsigned short* __restrict__ qlo,
    const unsigned char* __restrict__ mask,
    const unsigned short* __restrict__ wkf_hi,
    const unsigned short* __restrict__ wkf_lo,
    const float* __restrict__ bk,
    float* __restrict__ compat_out,
    float* __restrict__ compts)
{
  __shared__ unsigned short TH[64 * 128];
  __shared__ unsigned short TL[64 * 128];
  __shared__ float colsum[CCH];

  const int ch   = blockIdx.x;          // 0..15 candidate chunk (64 cands)
  const int b    = blockIdx.y;          // batch
  const int tid  = threadIdx.x;
  const int wave = tid >> 6;
  const int lane = tid & 63;
  const int l15  = lane & 15;
  const int quad = lane >> 4;

  if (tid < CCH) colsum[tid] = 0.f;

  // ---- stage cin chunk coalesced -> split -> swizzled LDS ----
  #pragma unroll
  for (int it = 0; it < 8; ++it) {
    const int lin = it * 256 + tid;        // 2048 x 16B = 64 rows x 512B
    const int row = lin >> 5;
    const int c16 = lin & 31;
    int grow = ch * CCH + row;
    if (grow > NCC - 1) grow = NCC - 1;    // tail clamp (cols masked later)
    const float4 x = *(const float4*)&cin[((size_t)b * NCC + grow) * EE + c16 * 4];
    const float xv[4] = {x.x, x.y, x.z, x.w};
    u16x4 h, l;
    #pragma unroll
    for (int j = 0; j < 4; ++j) {
      const unsigned short hb = f2bf(xv[j]);
      h[j] = hb;
      l[j] = f2bf(xv[j] - bf2f(hb));
    }
    const int byt = swz(row, c16 * 8);
    *(u16x4*)((char*)TH + byt) = h;
    *(u16x4*)((char*)TL + byt) = l;
  }
  __syncthreads();

  // ---------------- Phase A: K = C @ Wk + bk (in-place) ----------------
  {
    bf16x8 ahi[4], alo[4];
    const int arow = wave * 16 + l15;
    #pragma unroll
    for (int k4 = 0; k4 < 4; ++k4) {
      const int byt = swz(arow, k4 * 64 + quad * 16);
      ahi[k4] = *(const bf16x8*)((char*)TH + byt);
      alo[k4] = *(const bf16x8*)((char*)TL + byt);
    }
    #pragma unroll
    for (int nt = 0; nt < 8; ++nt) {
      const int n = nt * 16 + l15;
      f32x4 acc = (f32x4){0.f, 0.f, 0.f, 0.f};
      #pragma unroll
      for (int k4 = 0; k4 < 4; ++k4) {
        const size_t foff = (size_t)((nt * 4 + k4) * 64 + lane) * 8;
        const bf16x8 bh = ld8(&wkf_hi[foff]);
        const bf16x8 bl = ld8(&wkf_lo[foff]);
        acc = __builtin_amdgcn_mfma_f32_16x16x32_bf16(ahi[k4], bh, acc, 0, 0, 0);
        acc = __builtin_amdgcn_mfma_f32_16x16x32_bf16(ahi[k4], bl, acc, 0, 0, 0);
        acc = __builtin_amdgcn_mfma_f32_16x16x32_bf16(alo[k4], bh, acc, 0, 0, 0);
      }
      const float bkv = bk[n];
      #pragma unroll
      for (int r = 0; r < 4; ++r) {
        const int crow = wave * 16 + quad * 4 + r;
        const float v = acc[r] + bkv;
        const unsigned short hb = f2bf(v);
        const int byt = swz(crow, n * 2);
        *(unsigned short*)((char*)TH + byt) = hb;
        *(unsigned short*)((char*)TL + byt) = f2bf(v - bf2f(hb));
      }
    }
  }
  __syncthreads();

  // ---------------- Phase B: S = Q @ K^T ----------------
  {
    bf16x8 qh[4], ql[4];
    #pragma unroll
    for (int k4 = 0; k4 < 4; ++k4) {
      const size_t qoff = ((((size_t)b * 4 + wave) * 4 + k4) * 64 + lane) * 8;
      qh[k4] = ld8(&qhi[qoff]);
      ql[k4] = ld8(&qlo[qoff]);
    }

    f32x4 acc[4];
    #pragma unroll
    for (int nt = 0; nt < 4; ++nt) acc[nt] = (f32x4){0.f, 0.f, 0.f, 0.f};

    #pragma unroll
    for (int k4 = 0; k4 < 4; ++k4) {
      #pragma unroll
      for (int nt = 0; nt < 4; ++nt) {
        const int krow = nt * 16 + l15;
        const int byt = swz(krow, k4 * 64 + quad * 16);
        const bf16x8 khf = *(const bf16x8*)((char*)TH + byt);
        const bf16x8 klf = *(const bf16x8*)((char*)TL + byt);
        acc[nt] = __builtin_amdgcn_mfma_f32_16x16x32_bf16(qh[k4], khf, acc[nt], 0, 0, 0);
        acc[nt] = __builtin_amdgcn_mfma_f32_16x16x32_bf16(qh[k4], klf, acc[nt], 0, 0, 0);
        acc[nt] = __builtin_amdgcn_mfma_f32_16x16x32_bf16(ql[k4], khf, acc[nt], 0, 0, 0);
      }
    }

    // epilogue: fast tanh*10, mask, store, column sums
    #pragma unroll
    for (int nt = 0; nt < 4; ++nt) {
      const int jloc  = nt * 16 + l15;
      const int jglob = ch * CCH + jloc;
      const bool jok  = (jglob < NCC);
      float s4 = 0.f;
      #pragma unroll
      for (int r = 0; r < 4; ++r) {
        const int q = wave * 16 + quad * 4 + r;
        float v = tanh10_q(acc[nt][r]);
        if (jok) {
          if (mask[((size_t)b * NQ + q) * (NCC + 1) + 1 + jglob]) v = -INFINITY;
          compat_out[((size_t)b * NQ + q) * NCC + jglob] = v;
        }
        s4 += v;
      }
      s4 += __shfl_xor(s4, 16);
      s4 += __shfl_xor(s4, 32);
      if (lane < 16 && jok) atomicAdd(&colsum[jloc], s4);
    }
  }
  __syncthreads();

  if (tid < CCH) {
    const int jglob = ch * CCH + tid;
    if (jglob < NCC)
      compts[(size_t)b * 1024 + jglob] = colsum[tid] * (1.0f / (float)NQ);
  }
}

// ---------------------------------------------------------------------------
// Kernel 3: per-batch argmax over compts with cluster masking. (unchanged)
// ---------------------------------------------------------------------------
__global__ __launch_bounds__(256) void argmax_kernel(
    const float* __restrict__ compts,
    const unsigned char* __restrict__ clusters,
    const int* __restrict__ depot_id,
    float* __restrict__ out)
{
  __shared__ float redv[256];
  __shared__ int   redi[256];
  const int b   = blockIdx.x;
  const int tid = threadIdx.x;
  const int dep = depot_id[0];
  float bestv = -INFINITY;
  int   besti = 0x7fffffff;
  for (int j = tid; j < NCC; j += 256) {
    float t = compts[(size_t)b * 1024 + j];
    if (clusters[((size_t)b * DD + dep) * NCC + j]) t = -INFINITY;
    if (t > bestv || (t == bestv && j < besti)) { bestv = t; besti = j; }
  }
  redv[tid] = bestv; redi[tid] = besti;
  __syncthreads();
  if (tid == 0) {
    float bv = redv[0]; int bi = redi[0];
    for (int t = 1; t < 256; ++t) {
      if (redv[t] > bv || (redv[t] == bv && redi[t] < bi)) {
        bv = redv[t]; bi = redi[t];
      }
    }
    out[b] = (float)bi;
  }
}

// ---------------------------------------------------------------------------
extern "C" void kernel_launch(void* const* d_in, const int* in_sizes, int n_in,
                              void* d_out, int out_size, void* d_ws, size_t ws_size,
                              hipStream_t stream) {
  const float* hin      = (const float*)d_in[0];
  const float* cin      = (const float*)d_in[1];
  const unsigned char* mask     = (const unsigned char*)d_in[2];
  const unsigned char* clusters = (const unsigned char*)d_in[3];
  const int*   depot    = (const int*)d_in[4];
  const float* gWq = (const float*)d_in[5];
  const float* gbq = (const float*)d_in[6];
  const float* gWk = (const float*)d_in[7];
  const float* gbk = (const float*)d_in[8];
  const float* gWv = (const float*)d_in[9];
  const float* gbv = (const float*)d_in[10];
  const float* gWo = (const float*)d_in[11];
  const float* gbo = (const float*)d_in[12];
  const float* Wq  = (const float*)d_in[13];
  const float* bq  = (const float*)d_in[14];
  const float* Wk  = (const float*)d_in[15];
  const float* bk  = (const float*)d_in[16];
  float* out   = (float*)d_out;
  float* compat_out = out + NB;

  // ws layout: qhi (8 MiB) | qlo (8 MiB) | compts (2 MiB) | gwt_hi | gwt_lo
  //            | wkf_hi (32 KiB) | wkf_lo (32 KiB)
  unsigned short* qhi    = (unsigned short*)d_ws;
  unsigned short* qlo    = qhi + (size_t)NB * 4 * 4 * 64 * 8;
  float*          compts = (float*)(qlo + (size_t)NB * 4 * 4 * 64 * 8);
  unsigned short* gwt_hi = (unsigned short*)((char*)compts + (size_t)NB * 1024 * 4);
  unsigned short* gwt_lo = gwt_hi + (size_t)14 * 16384;
  unsigned short* wkf_hi = gwt_lo + (size_t)14 * 16384;
  unsigned short* wkf_lo = wkf_hi + (size_t)16384;

  wprep_kernel<<<896, 256, 0, stream>>>(gWq, gWk, gWv, gWo, Wq, Wk,
                                        gwt_hi, gwt_lo, wkf_hi, wkf_lo);
  gat_query_mfma<<<NB, 512, 0, stream>>>(hin, gwt_hi, gwt_lo,
                                         gbq, gbk, gbv, gbo, bq, qhi, qlo);
  compat_mfma_kernel<<<dim3(16, NB), 256, 0, stream>>>(
      cin, qhi, qlo, mask, wkf_hi, wkf_lo, bk, compat_out, compts);
  argmax_kernel<<<NB, 256, 0, stream>>>(compts, clusters, depot, out);
}

// Round 4
// 777.742 us; speedup vs baseline: 1.2342x; 1.0653x over previous
//
#include <hip/hip_runtime.h>
#include <math.h>

// Problem constants (from reference)
#define NB   512    // batch
#define NQ   64     // queries
#define NCC  1000   // candidates
#define EE   128    // embed
#define HH   8      // heads
#define HDD  16     // head dim
#define NL   3      // GAT layers
#define DD   4      // cluster depth
#define CCH  64     // candidates per compat block
#define XP   136    // LDS pitch (ushort) for gat [64][*] views (272B rows, 16B-aligned)
#define VP   72     // LDS pitch (ushort) for gat V^T [128][64] view (144B rows)
#define SCRN 9216   // scratch u16 count per part: max(64*136=8704, 128*72=9216)

typedef __bf16 bf16x8 __attribute__((ext_vector_type(8)));
typedef unsigned short u16x8 __attribute__((ext_vector_type(8)));
typedef unsigned short u16x4 __attribute__((ext_vector_type(4)));
typedef unsigned int   u32x4 __attribute__((ext_vector_type(4)));
typedef float f32x4  __attribute__((ext_vector_type(4)));
typedef float f32x16 __attribute__((ext_vector_type(16)));

__device__ __forceinline__ unsigned short f2bf(float x) {
  union { float f; unsigned u; } v; v.f = x;
  unsigned r = (v.u + 0x7fffu + ((v.u >> 16) & 1u)) >> 16;
  return (unsigned short)r;
}
__device__ __forceinline__ float bf2f(unsigned short h) {
  union { unsigned u; float f; } v; v.u = ((unsigned)h) << 16;
  return v.f;
}
__device__ __forceinline__ bf16x8 ld8(const unsigned short* p) {
  return __builtin_bit_cast(bf16x8, *(const u16x8*)p);
}
// 10*tanh(s*0.25) = 10 - 20/(exp(s*0.5)+1); exact saturation at +/-10.
__device__ __forceinline__ float tanh10_q(float s) {
  const float e = __expf(s * 0.5f);
  return 10.f - 20.f * __builtin_amdgcn_rcpf(e + 1.f);
}
// XOR-swizzled byte offset inside a [64][128]-u16 (256B-row) LDS tile (compat)
__device__ __forceinline__ int swz(int row, int cb) {
  return row * 256 + (cb ^ ((row & 7) << 4));
}

// ---------------------------------------------------------------------------
// Kernel 0: weight prep. ALL 14 matrices -> FRAGMENT-LINEAR bf16 hi/lo:
//  gwf[m][((nt*4+k4)*64 + lane)*8 + j] = W[k4*32+(lane>>4)*8+j][nt*16+(lane&15)]
//  (B-fragment loads become lane-consecutive 16B -> 1KB coalesced wave-loads).
//  m = l*4 + {0:Wq,1:Wk,2:Wv,3:Wo} for l in 0..2, m=12: final Wq, m=13: final Wk
//  (m=13 doubles as the compat kernel's wkf).
// ---------------------------------------------------------------------------
__global__ __launch_bounds__(256) void wprep_kernel(
    const float* __restrict__ gWq, const float* __restrict__ gWk,
    const float* __restrict__ gWv, const float* __restrict__ gWo,
    const float* __restrict__ Wq,  const float* __restrict__ Wk,
    unsigned short* __restrict__ gwf_hi, unsigned short* __restrict__ gwf_lo)
{
  const int idx = blockIdx.x * 256 + threadIdx.x;   // 896 blocks -> 14*16384
  const int m = idx >> 14;
  const int r = idx & 16383;
  const int k = r >> 7, n = r & 127;
  const float* src;
  if (m < 12) {
    const int l = m >> 2, w = m & 3;
    src = (w == 0 ? gWq : w == 1 ? gWk : w == 2 ? gWv : gWo) + l * 16384;
  } else if (m == 12) src = Wq;
  else                src = Wk;
  const float v = src[k * EE + n];
  const unsigned short h  = f2bf(v);
  const unsigned short lo = f2bf(v - bf2f(h));
  const int nt = n >> 4, l15 = n & 15;
  const int k4 = k >> 5, qd = (k >> 3) & 3, j = k & 7;
  const size_t off = (size_t)m * 16384 + (((nt * 4 + k4) * 64) + qd * 16 + l15) * 8 + j;
  gwf_hi[off] = h;
  gwf_lo[off] = lo;
}

// ---------------------------------------------------------------------------
// Kernel 1: MFMA GAT (3 fused MHA layers) + final query projection.
// One block per batch, 512 threads = 8 waves; wave w owns head w / col-tile w.
// Per-head P1: wave w computes ALL 64 rows of Q_h,K_h,V_h (cols h*16..+16).
// ONE shared scratch (SH/SL) used sequentially with wave-private regions:
//   QK view [64][136]: wave w owns cols w*16..+16 (Q wr/rd, K wr/rd, later O)
//   VT view [128][72]: wave w owns rows w*16..+16 (V^T wr/rd)
// Barriers: B1 after QK-view reads (before V^T writes), B2 after V^T reads
// (before O writes), B3 after O writes (before cross-wave P3 reads), B4 after
// P3's X update. LDS = 2*(64*136 + 9216)*2B = 70 KB -> 2 blocks/CU.
// MFMA fragment layouts (gfx950, per guide m89/m91/m74/m101/m214):
//  16x16x32: A row=lane&15,k=(lane>>4)*8+j; B col=lane&15,k=(lane>>4)*8+j;
//            C col=lane&15,row=(lane>>4)*4+reg.
//  32x32x16: A row=lane&31,k=(lane>>5)*8+j; B col=lane&31,k=(lane>>5)*8+j;
//            C col=lane&31,row=(reg&3)+8*(reg>>2)+4*(lane>>5).
// ---------------------------------------------------------------------------
__global__ __launch_bounds__(512, 4) void gat_query_mfma(
    const float* __restrict__ hin,
    const unsigned short* __restrict__ gwf_hi,
    const unsigned short* __restrict__ gwf_lo,
    const float* __restrict__ gbq, const float* __restrict__ gbk,
    const float* __restrict__ gbv, const float* __restrict__ gbo,
    const float* __restrict__ bq,
    unsigned short* __restrict__ qhi, unsigned short* __restrict__ qlo)
{
  __shared__ unsigned short XH[64 * XP], XL[64 * XP];
  __shared__ unsigned short SH[SCRN],    SL[SCRN];

  const int b    = blockIdx.x;
  const int tid  = threadIdx.x;
  const int wid  = tid >> 6;
  const int lane = tid & 63;
  const int l15  = lane & 15;
  const int quad = lane >> 4;
  const int col  = lane & 31;
  const int hi32 = lane >> 5;
  const int h    = wid;            // head / col-tile owner
  const int r0p3 = (wid >> 1) * 16;  // P3 row tile
  const int nh   = wid & 1;          // P3 col half

  // load + split X
  for (int idx = tid; idx < NQ * EE; idx += 512) {
    const float v = hin[(size_t)b * NQ * EE + idx];
    const int r = idx >> 7, c = idx & 127;
    const unsigned short hh = f2bf(v);
    XH[r * XP + c] = hh;
    XL[r * XP + c] = f2bf(v - bf2f(hh));
  }
  __syncthreads();

  for (int l = 0; l < NL; ++l) {
    // ---------------- P1: creg[m][mt] = (X @ W_m)[all rows, head cols] ------
    f32x4 creg[3][4];
    #pragma unroll
    for (int mt = 0; mt < 4; ++mt) {
      bf16x8 axh[4], axl[4];
      #pragma unroll
      for (int k4 = 0; k4 < 4; ++k4) {
        axh[k4] = ld8(&XH[(mt * 16 + l15) * XP + k4 * 32 + quad * 8]);
        axl[k4] = ld8(&XL[(mt * 16 + l15) * XP + k4 * 32 + quad * 8]);
      }
      #pragma unroll
      for (int m = 0; m < 3; ++m) {
        const unsigned short* WH = gwf_hi + (size_t)(l * 4 + m) * 16384;
        const unsigned short* WL = gwf_lo + (size_t)(l * 4 + m) * 16384;
        f32x4 acc = (f32x4){0.f, 0.f, 0.f, 0.f};
        #pragma unroll
        for (int k4 = 0; k4 < 4; ++k4) {
          const size_t foff = (size_t)((h * 4 + k4) * 64 + lane) * 8;
          const bf16x8 bh = ld8(&WH[foff]);
          const bf16x8 bl = ld8(&WL[foff]);
          acc = __builtin_amdgcn_mfma_f32_16x16x32_bf16(axh[k4], bh, acc, 0, 0, 0);
          acc = __builtin_amdgcn_mfma_f32_16x16x32_bf16(axh[k4], bl, acc, 0, 0, 0);
          acc = __builtin_amdgcn_mfma_f32_16x16x32_bf16(axl[k4], bh, acc, 0, 0, 0);
        }
        creg[m][mt] = acc;
      }
    }

    // ---------------- Q: write scratch (own cols), read B-frags ------------
    {
      const float bv = gbq[l * EE + h * 16 + l15];
      #pragma unroll
      for (int mt = 0; mt < 4; ++mt)
        #pragma unroll
        for (int r = 0; r < 4; ++r) {
          const float v = creg[0][mt][r] + bv;
          const unsigned short hh = f2bf(v);
          const int o = (mt * 16 + quad * 4 + r) * XP + h * 16 + l15;
          SH[o] = hh;
          SL[o] = f2bf(v - bf2f(hh));
        }
    }
    bf16x8 qbh[2], qbl[2];
    #pragma unroll
    for (int t = 0; t < 2; ++t) {
      qbh[t] = ld8(&SH[(t * 32 + col) * XP + h * 16 + hi32 * 8]);
      qbl[t] = ld8(&SL[(t * 32 + col) * XP + h * 16 + hi32 * 8]);
    }

    // ---------------- K: same (overwrites Q cols; Q already in regs) -------
    {
      const float bv = gbk[l * EE + h * 16 + l15];
      #pragma unroll
      for (int mt = 0; mt < 4; ++mt)
        #pragma unroll
        for (int r = 0; r < 4; ++r) {
          const float v = creg[1][mt][r] + bv;
          const unsigned short hh = f2bf(v);
          const int o = (mt * 16 + quad * 4 + r) * XP + h * 16 + l15;
          SH[o] = hh;
          SL[o] = f2bf(v - bf2f(hh));
        }
    }
    bf16x8 akh[2], akl[2];
    #pragma unroll
    for (int t = 0; t < 2; ++t) {
      akh[t] = ld8(&SH[(t * 32 + col) * XP + h * 16 + hi32 * 8]);
      akl[t] = ld8(&SL[(t * 32 + col) * XP + h * 16 + hi32 * 8]);
    }

    // ---------------- S^T = K @ Q^T, softmax, P-frag pack ------------------
    bf16x8 pah[2][4], pal[2][4];   // PV A-frags [qt][ks]
    #pragma unroll
    for (int qt = 0; qt < 2; ++qt) {
      f32x16 sAcc[2];
      #pragma unroll
      for (int kt = 0; kt < 2; ++kt) {
        #pragma unroll
        for (int i = 0; i < 16; ++i) sAcc[kt][i] = 0.f;
        sAcc[kt] = __builtin_amdgcn_mfma_f32_32x32x16_bf16(akh[kt], qbh[qt], sAcc[kt], 0, 0, 0);
        sAcc[kt] = __builtin_amdgcn_mfma_f32_32x32x16_bf16(akh[kt], qbl[qt], sAcc[kt], 0, 0, 0);
        sAcc[kt] = __builtin_amdgcn_mfma_f32_32x32x16_bf16(akl[kt], qbh[qt], sAcc[kt], 0, 0, 0);
      }
      float p[2][16];
      float mx = -INFINITY;
      #pragma unroll
      for (int kt = 0; kt < 2; ++kt)
        #pragma unroll
        for (int r = 0; r < 16; ++r) {
          p[kt][r] = sAcc[kt][r] * 0.25f;
          mx = fmaxf(mx, p[kt][r]);
        }
      mx = fmaxf(mx, __shfl_xor(mx, 32));
      float sum = 0.f;
      #pragma unroll
      for (int kt = 0; kt < 2; ++kt)
        #pragma unroll
        for (int r = 0; r < 16; ++r) {
          p[kt][r] = exp2f((p[kt][r] - mx) * 1.4426950408889634f);
          sum += p[kt][r];
        }
      sum += __shfl_xor(sum, 32);
      const float inv = 1.f / sum;

      unsigned pkh[2][8], pkl[2][8], swh[2][8], swl[2][8];
      #pragma unroll
      for (int kt = 0; kt < 2; ++kt)
        #pragma unroll
        for (int w = 0; w < 8; ++w) {
          const float v0 = p[kt][w * 2]     * inv;
          const float v1 = p[kt][w * 2 + 1] * inv;
          const unsigned short h0 = f2bf(v0);
          const unsigned short l0 = f2bf(v0 - bf2f(h0));
          const unsigned short h1 = f2bf(v1);
          const unsigned short l1 = f2bf(v1 - bf2f(h1));
          pkh[kt][w] = (unsigned)h0 | ((unsigned)h1 << 16);
          pkl[kt][w] = (unsigned)l0 | ((unsigned)l1 << 16);
          swh[kt][w] = (unsigned)__shfl_xor((int)pkh[kt][w], 32);
          swl[kt][w] = (unsigned)__shfl_xor((int)pkl[kt][w], 32);
        }
      const bool top = (hi32 != 0);
      #pragma unroll
      for (int ks = 0; ks < 4; ++ks) {
        const int kt = ks >> 1, hf = ks & 1;
        u32x4 wh, wl;
        wh[0] = top ? swh[kt][4 * hf + 2] : pkh[kt][4 * hf + 0];
        wh[1] = top ? swh[kt][4 * hf + 3] : pkh[kt][4 * hf + 1];
        wh[2] = top ? pkh[kt][4 * hf + 2] : swh[kt][4 * hf + 0];
        wh[3] = top ? pkh[kt][4 * hf + 3] : swh[kt][4 * hf + 1];
        wl[0] = top ? swl[kt][4 * hf + 2] : pkl[kt][4 * hf + 0];
        wl[1] = top ? swl[kt][4 * hf + 3] : pkl[kt][4 * hf + 1];
        wl[2] = top ? pkl[kt][4 * hf + 2] : swl[kt][4 * hf + 0];
        wl[3] = top ? pkl[kt][4 * hf + 3] : swl[kt][4 * hf + 1];
        pah[qt][ks] = __builtin_bit_cast(bf16x8, wh);
        pal[qt][ks] = __builtin_bit_cast(bf16x8, wl);
      }
    }
    __syncthreads();   // B1: all waves done reading QK-view

    // ---------------- V: write V^T view (own rows), read B-frags -----------
    {
      const float bv = gbv[l * EE + h * 16 + l15];
      #pragma unroll
      for (int mt = 0; mt < 4; ++mt) {
        u16x4 hv, lv;
        #pragma unroll
        for (int r = 0; r < 4; ++r) {
          const float v = creg[2][mt][r] + bv;
          const unsigned short hh = f2bf(v);
          hv[r] = hh;
          lv[r] = f2bf(v - bf2f(hh));
        }
        *(u16x4*)&SH[(h * 16 + l15) * VP + mt * 16 + quad * 4] = hv;
        *(u16x4*)&SL[(h * 16 + l15) * VP + mt * 16 + quad * 4] = lv;
      }
    }
    bf16x8 bvh[4], bvl[4];
    {
      const int vrow = h * 16 + (col & 15);
      #pragma unroll
      for (int ks = 0; ks < 4; ++ks) {
        bvh[ks] = ld8(&SH[vrow * VP + ks * 16 + hi32 * 8]);
        bvl[ks] = ld8(&SL[vrow * VP + ks * 16 + hi32 * 8]);
      }
    }

    // ---------------- PV -> accO ----------------
    f32x16 accO[2];
    #pragma unroll
    for (int qt = 0; qt < 2; ++qt) {
      #pragma unroll
      for (int i = 0; i < 16; ++i) accO[qt][i] = 0.f;
      #pragma unroll
      for (int ks = 0; ks < 4; ++ks) {
        accO[qt] = __builtin_amdgcn_mfma_f32_32x32x16_bf16(pah[qt][ks], bvh[ks], accO[qt], 0, 0, 0);
        accO[qt] = __builtin_amdgcn_mfma_f32_32x32x16_bf16(pah[qt][ks], bvl[ks], accO[qt], 0, 0, 0);
        accO[qt] = __builtin_amdgcn_mfma_f32_32x32x16_bf16(pal[qt][ks], bvh[ks], accO[qt], 0, 0, 0);
      }
    }
    __syncthreads();   // B2: all waves done reading V^T view

    // ---------------- O write (QK view, own cols) ----------------
    if (col < 16) {
      #pragma unroll
      for (int qt = 0; qt < 2; ++qt)
        #pragma unroll
        for (int r = 0; r < 16; ++r) {
          const int qrow = qt * 32 + (r & 3) + 8 * (r >> 2) + 4 * hi32;
          const float v = accO[qt][r];
          const unsigned short hh = f2bf(v);
          SH[qrow * XP + h * 16 + col] = hh;
          SL[qrow * XP + h * 16 + col] = f2bf(v - bf2f(hh));
        }
    }
    __syncthreads();   // B3: O complete, cross-wave readable

    // ---------------- P3: X += O @ Wo + bo ----------------
    {
      bf16x8 aoh[4], aol[4];
      #pragma unroll
      for (int k4 = 0; k4 < 4; ++k4) {
        aoh[k4] = ld8(&SH[(r0p3 + l15) * XP + k4 * 32 + quad * 8]);
        aol[k4] = ld8(&SL[(r0p3 + l15) * XP + k4 * 32 + quad * 8]);
      }
      const unsigned short* WH = gwf_hi + (size_t)(l * 4 + 3) * 16384;
      const unsigned short* WL = gwf_lo + (size_t)(l * 4 + 3) * 16384;
      #pragma unroll
      for (int ntl = 0; ntl < 4; ++ntl) {
        const int n = (nh * 4 + ntl) * 16 + l15;
        f32x4 acc = (f32x4){0.f, 0.f, 0.f, 0.f};
        #pragma unroll
        for (int k4 = 0; k4 < 4; ++k4) {
          const size_t foff = (size_t)(((nh * 4 + ntl) * 4 + k4) * 64 + lane) * 8;
          const bf16x8 bh = ld8(&WH[foff]);
          const bf16x8 bl = ld8(&WL[foff]);
          acc = __builtin_amdgcn_mfma_f32_16x16x32_bf16(aoh[k4], bh, acc, 0, 0, 0);
          acc = __builtin_amdgcn_mfma_f32_16x16x32_bf16(aoh[k4], bl, acc, 0, 0, 0);
          acc = __builtin_amdgcn_mfma_f32_16x16x32_bf16(aol[k4], bh, acc, 0, 0, 0);
        }
        const float bv = gbo[l * EE + n];
        #pragma unroll
        for (int r = 0; r < 4; ++r) {
          const int crow = r0p3 + quad * 4 + r;
          const float xo = bf2f(XH[crow * XP + n]) + bf2f(XL[crow * XP + n]);
          const float v = xo + acc[r] + bv;
          const unsigned short hh = f2bf(v);
          XH[crow * XP + n] = hh;
          XL[crow * XP + n] = f2bf(v - bf2f(hh));
        }
      }
    }
    __syncthreads();   // B4: X stable, scratch free
  }

  // ---------------- final query projection (mat 12) -> scratch -------------
  {
    const unsigned short* WH = gwf_hi + (size_t)12 * 16384;
    const unsigned short* WL = gwf_lo + (size_t)12 * 16384;
    const float bv = bq[h * 16 + l15];
    #pragma unroll
    for (int mt = 0; mt < 4; ++mt) {
      bf16x8 axh[4], axl[4];
      #pragma unroll
      for (int k4 = 0; k4 < 4; ++k4) {
        axh[k4] = ld8(&XH[(mt * 16 + l15) * XP + k4 * 32 + quad * 8]);
        axl[k4] = ld8(&XL[(mt * 16 + l15) * XP + k4 * 32 + quad * 8]);
      }
      f32x4 acc = (f32x4){0.f, 0.f, 0.f, 0.f};
      #pragma unroll
      for (int k4 = 0; k4 < 4; ++k4) {
        const size_t foff = (size_t)((h * 4 + k4) * 64 + lane) * 8;
        const bf16x8 bh = ld8(&WH[foff]);
        const bf16x8 bl = ld8(&WL[foff]);
        acc = __builtin_amdgcn_mfma_f32_16x16x32_bf16(axh[k4], bh, acc, 0, 0, 0);
        acc = __builtin_amdgcn_mfma_f32_16x16x32_bf16(axh[k4], bl, acc, 0, 0, 0);
        acc = __builtin_amdgcn_mfma_f32_16x16x32_bf16(axl[k4], bh, acc, 0, 0, 0);
      }
      #pragma unroll
      for (int r = 0; r < 4; ++r) {
        const float v = acc[r] + bv;
        const unsigned short hh = f2bf(v);
        const int o = (mt * 16 + quad * 4 + r) * XP + h * 16 + l15;
        SH[o] = hh;
        SL[o] = f2bf(v - bf2f(hh));
      }
    }
  }
  __syncthreads();   // B5: query tile complete

  // repack query to fragment-linear qhi/qlo: [b][wc][k4][lane][8]
  for (int it = 0; it < 4; ++it) {
    const int idx  = it * 512 + tid;       // 0..2047
    const int part = idx >> 10;            // 0 = hi, 1 = lo
    const int id2  = idx & 1023;
    const int wc   = id2 >> 8;
    const int k4   = (id2 >> 6) & 3;
    const int ln   = id2 & 63;
    const int row  = wc * 16 + (ln & 15);
    const int colu = k4 * 32 + (ln >> 4) * 8;
    const unsigned short* S = part ? SL : SH;
    const u16x8 v = *(const u16x8*)&S[row * XP + colu];
    unsigned short* D = part ? qlo : qhi;
    *(u16x8*)&D[((((size_t)b * 4 + wc) * 4 + k4) * 64 + ln) * 8] = v;
  }
}

// ---------------------------------------------------------------------------
// Kernel 2: MFMA compat. One block per (64-candidate chunk, batch). (unchanged)
// ---------------------------------------------------------------------------
__global__ __launch_bounds__(256, 4) void compat_mfma_kernel(
    const float* __restrict__ cin,
    const unsigned short* __restrict__ qhi,
    const unsigned short* __restrict__ qlo,
    const unsigned char* __restrict__ mask,
    const unsigned short* __restrict__ wkf_hi,
    const unsigned short* __restrict__ wkf_lo,
    const float* __restrict__ bk,
    float* __restrict__ compat_out,
    float* __restrict__ compts)
{
  __shared__ unsigned short TH[64 * 128];
  __shared__ unsigned short TL[64 * 128];
  __shared__ float colsum[CCH];

  const int ch   = blockIdx.x;          // 0..15 candidate chunk (64 cands)
  const int b    = blockIdx.y;          // batch
  const int tid  = threadIdx.x;
  const int wave = tid >> 6;
  const int lane = tid & 63;
  const int l15  = lane & 15;
  const int quad = lane >> 4;

  if (tid < CCH) colsum[tid] = 0.f;

  // ---- stage cin chunk coalesced -> split -> swizzled LDS ----
  #pragma unroll
  for (int it = 0; it < 8; ++it) {
    const int lin = it * 256 + tid;        // 2048 x 16B = 64 rows x 512B
    const int row = lin >> 5;
    const int c16 = lin & 31;
    int grow = ch * CCH + row;
    if (grow > NCC - 1) grow = NCC - 1;    // tail clamp (cols masked later)
    const float4 x = *(const float4*)&cin[((size_t)b * NCC + grow) * EE + c16 * 4];
    const float xv[4] = {x.x, x.y, x.z, x.w};
    u16x4 h, l;
    #pragma unroll
    for (int j = 0; j < 4; ++j) {
      const unsigned short hb = f2bf(xv[j]);
      h[j] = hb;
      l[j] = f2bf(xv[j] - bf2f(hb));
    }
    const int byt = swz(row, c16 * 8);
    *(u16x4*)((char*)TH + byt) = h;
    *(u16x4*)((char*)TL + byt) = l;
  }
  __syncthreads();

  // ---------------- Phase A: K = C @ Wk + bk (in-place) ----------------
  {
    bf16x8 ahi[4], alo[4];
    const int arow = wave * 16 + l15;
    #pragma unroll
    for (int k4 = 0; k4 < 4; ++k4) {
      const int byt = swz(arow, k4 * 64 + quad * 16);
      ahi[k4] = *(const bf16x8*)((char*)TH + byt);
      alo[k4] = *(const bf16x8*)((char*)TL + byt);
    }
    #pragma unroll
    for (int nt = 0; nt < 8; ++nt) {
      const int n = nt * 16 + l15;
      f32x4 acc = (f32x4){0.f, 0.f, 0.f, 0.f};
      #pragma unroll
      for (int k4 = 0; k4 < 4; ++k4) {
        const size_t foff = (size_t)((nt * 4 + k4) * 64 + lane) * 8;
        const bf16x8 bh = ld8(&wkf_hi[foff]);
        const bf16x8 bl = ld8(&wkf_lo[foff]);
        acc = __builtin_amdgcn_mfma_f32_16x16x32_bf16(ahi[k4], bh, acc, 0, 0, 0);
        acc = __builtin_amdgcn_mfma_f32_16x16x32_bf16(ahi[k4], bl, acc, 0, 0, 0);
        acc = __builtin_amdgcn_mfma_f32_16x16x32_bf16(alo[k4], bh, acc, 0, 0, 0);
      }
      const float bkv = bk[n];
      #pragma unroll
      for (int r = 0; r < 4; ++r) {
        const int crow = wave * 16 + quad * 4 + r;
        const float v = acc[r] + bkv;
        const unsigned short hb = f2bf(v);
        const int byt = swz(crow, n * 2);
        *(unsigned short*)((char*)TH + byt) = hb;
        *(unsigned short*)((char*)TL + byt) = f2bf(v - bf2f(hb));
      }
    }
  }
  __syncthreads();

  // ---------------- Phase B: S = Q @ K^T ----------------
  {
    bf16x8 qh[4], ql[4];
    #pragma unroll
    for (int k4 = 0; k4 < 4; ++k4) {
      const size_t qoff = ((((size_t)b * 4 + wave) * 4 + k4) * 64 + lane) * 8;
      qh[k4] = ld8(&qhi[qoff]);
      ql[k4] = ld8(&qlo[qoff]);
    }

    f32x4 acc[4];
    #pragma unroll
    for (int nt = 0; nt < 4; ++nt) acc[nt] = (f32x4){0.f, 0.f, 0.f, 0.f};

    #pragma unroll
    for (int k4 = 0; k4 < 4; ++k4) {
      #pragma unroll
      for (int nt = 0; nt < 4; ++nt) {
        const int krow = nt * 16 + l15;
        const int byt = swz(krow, k4 * 64 + quad * 16);
        const bf16x8 khf = *(const bf16x8*)((char*)TH + byt);
        const bf16x8 klf = *(const bf16x8*)((char*)TL + byt);
        acc[nt] = __builtin_amdgcn_mfma_f32_16x16x32_bf16(qh[k4], khf, acc[nt], 0, 0, 0);
        acc[nt] = __builtin_amdgcn_mfma_f32_16x16x32_bf16(qh[k4], klf, acc[nt], 0, 0, 0);
        acc[nt] = __builtin_amdgcn_mfma_f32_16x16x32_bf16(ql[k4], khf, acc[nt], 0, 0, 0);
      }
    }

    // epilogue: fast tanh*10, mask, store, column sums
    #pragma unroll
    for (int nt = 0; nt < 4; ++nt) {
      const int jloc  = nt * 16 + l15;
      const int jglob = ch * CCH + jloc;
      const bool jok  = (jglob < NCC);
      float s4 = 0.f;
      #pragma unroll
      for (int r = 0; r < 4; ++r) {
        const int q = wave * 16 + quad * 4 + r;
        float v = tanh10_q(acc[nt][r]);
        if (jok) {
          if (mask[((size_t)b * NQ + q) * (NCC + 1) + 1 + jglob]) v = -INFINITY;
          compat_out[((size_t)b * NQ + q) * NCC + jglob] = v;
        }
        s4 += v;
      }
      s4 += __shfl_xor(s4, 16);
      s4 += __shfl_xor(s4, 32);
      if (lane < 16 && jok) atomicAdd(&colsum[jloc], s4);
    }
  }
  __syncthreads();

  if (tid < CCH) {
    const int jglob = ch * CCH + tid;
    if (jglob < NCC)
      compts[(size_t)b * 1024 + jglob] = colsum[tid] * (1.0f / (float)NQ);
  }
}

// ---------------------------------------------------------------------------
// Kernel 3: per-batch argmax over compts with cluster masking. (unchanged)
// ---------------------------------------------------------------------------
__global__ __launch_bounds__(256) void argmax_kernel(
    const float* __restrict__ compts,
    const unsigned char* __restrict__ clusters,
    const int* __restrict__ depot_id,
    float* __restrict__ out)
{
  __shared__ float redv[256];
  __shared__ int   redi[256];
  const int b   = blockIdx.x;
  const int tid = threadIdx.x;
  const int dep = depot_id[0];
  float bestv = -INFINITY;
  int   besti = 0x7fffffff;
  for (int j = tid; j < NCC; j += 256) {
    float t = compts[(size_t)b * 1024 + j];
    if (clusters[((size_t)b * DD + dep) * NCC + j]) t = -INFINITY;
    if (t > bestv || (t == bestv && j < besti)) { bestv = t; besti = j; }
  }
  redv[tid] = bestv; redi[tid] = besti;
  __syncthreads();
  if (tid == 0) {
    float bv = redv[0]; int bi = redi[0];
    for (int t = 1; t < 256; ++t) {
      if (redv[t] > bv || (redv[t] == bv && redi[t] < bi)) {
        bv = redv[t]; bi = redi[t];
      }
    }
    out[b] = (float)bi;
  }
}

// ---------------------------------------------------------------------------
extern "C" void kernel_launch(void* const* d_in, const int* in_sizes, int n_in,
                              void* d_out, int out_size, void* d_ws, size_t ws_size,
                              hipStream_t stream) {
  const float* hin      = (const float*)d_in[0];
  const float* cin      = (const float*)d_in[1];
  const unsigned char* mask     = (const unsigned char*)d_in[2];
  const unsigned char* clusters = (const unsigned char*)d_in[3];
  const int*   depot    = (const int*)d_in[4];
  const float* gWq = (const float*)d_in[5];
  const float* gbq = (const float*)d_in[6];
  const float* gWk = (const float*)d_in[7];
  const float* gbk = (const float*)d_in[8];
  const float* gWv = (const float*)d_in[9];
  const float* gbv = (const float*)d_in[10];
  const float* gWo = (const float*)d_in[11];
  const float* gbo = (const float*)d_in[12];
  const float* Wq  = (const float*)d_in[13];
  const float* bq  = (const float*)d_in[14];
  const float* Wk  = (const float*)d_in[15];
  const float* bk  = (const float*)d_in[16];
  float* out   = (float*)d_out;
  float* compat_out = out + NB;

  // ws layout: qhi (4 MiB) | qlo (4 MiB) | compts (2 MiB) | gwf_hi (448 KiB) | gwf_lo
  unsigned short* qhi    = (unsigned short*)d_ws;
  unsigned short* qlo    = qhi + (size_t)NB * 4 * 4 * 64 * 8;
  float*          compts = (float*)(qlo + (size_t)NB * 4 * 4 * 64 * 8);
  unsigned short* gwf_hi = (unsigned short*)((char*)compts + (size_t)NB * 1024 * 4);
  unsigned short* gwf_lo = gwf_hi + (size_t)14 * 16384;
  unsigned short* wkf_hi = gwf_hi + (size_t)13 * 16384;   // mat 13 = final Wk
  unsigned short* wkf_lo = gwf_lo + (size_t)13 * 16384;

  wprep_kernel<<<896, 256, 0, stream>>>(gWq, gWk, gWv, gWo, Wq, Wk,
                                        gwf_hi, gwf_lo);
  gat_query_mfma<<<NB, 512, 0, stream>>>(hin, gwf_hi, gwf_lo,
                                         gbq, gbk, gbv, gbo, bq, qhi, qlo);
  compat_mfma_kernel<<<dim3(16, NB), 256, 0, stream>>>(
      cin, qhi, qlo, mask, wkf_hi, wkf_lo, bk, compat_out, compts);
  argmax_kernel<<<NB, 256, 0, stream>>>(compts, clusters, depot, out);
}